// Round 4
// baseline (1057.224 us; speedup 1.0000x reference)
//
#include <hip/hip_runtime.h>

// SimpleCRA round 9: ZERO-LDS register GEMM (discriminating experiment).
// r5/r7/r8 falsified bank-conflict, latency-pipelining, and traffic theories:
// per-block staging delivery pinned ~2-3.5 B/cy regardless of schedule/bytes.
// This round removes the entire barrier-lockstep global_load_lds structure:
// MFMA frags load DIRECTLY global->VGPR (packed images make each frag set a
// contiguous, perfectly coalesced 1KB wave-load). B' (4 MiB) is L2-resident;
// A panels are L2-shared by the 16 co-dispatched colb blocks of each mb.
// No barriers / DMA / LDS in the main loop; manual 2-deep frag prefetch.
// Tiling, chunk order g=0..47 (ah*bh, al*bh, ah*bl) and per-acc MFMA order
// identical to round 5 => bitwise-identical scores; EPS/tie-recheck path
// unchanged. Pack/merge/gather/recheck = round 5 verbatim.

#define D_DIM    512
#define K_CODES  2048
#define N_ROWS   32768
#define EPS_GAP  1e-5f
#define LOSS_SCALE (1.0f / 16777216.0f)   // 1/(N_ROWS*D_DIM)

typedef __attribute__((ext_vector_type(8))) short short8;   // 8 bf16 (4 VGPR)
typedef __attribute__((ext_vector_type(4))) float f32x4;    // MFMA C/D

__device__ __forceinline__ void split_bf16(float f, unsigned short& h, unsigned short& l) {
    unsigned u = __float_as_uint(f);
    h = (unsigned short)(u >> 16);                       // truncation split
    float hr = __uint_as_float(u & 0xFFFF0000u);
    l = (unsigned short)(__float_as_uint(f - hr) >> 16);
}

// insert candidate into sorted-2 list ordered by (val, idx) — total order,
// merge-order independent; matches numpy first-occurrence argmin.
__device__ __forceinline__ void merge_cand(float s, int idx, float& v1, int& i1, float& v2, int& i2) {
    if (s < v1 || (s == v1 && idx < i1)) { v2 = v1; i2 = i1; v1 = s; i1 = idx; }
    else if (s < v2 || (s == v2 && idx < i2)) { v2 = s; i2 = idx; }
}

// ---------------------------------------------------------------------------
// Kernel 1: pack A' images. Block = one mb (128 mean-rows); layout
// [mb 256][ach 32][row 128][k 32] shorts, ach 0-15 = Ah, 16-31 = Al.
// ---------------------------------------------------------------------------
__global__ __launch_bounds__(256, 1)
void cra_pack_a(const float* __restrict__ ce,
                unsigned short* __restrict__ Ap)
{
    const int tid = threadIdx.x;
    const int mb  = blockIdx.x;
    const int rq  = tid >> 5;            // row slice 0..7
    const int dq  = tid & 31;            // 16-float span index
    const int dbase = dq * 16;
    const int ach = dq >> 1;             // 0..15
    const int k0  = (dq & 1) * 16;

    #pragma unroll 2
    for (int p = 0; p < 16; ++p) {
        const int r  = p * 8 + rq;       // 0..127
        const int gr = mb * 128 + r;
        const float* a0 = ce + (size_t)(2 * gr) * D_DIM + dbase;
        const float* a1 = a0 + D_DIM;
        float4 x0[4], x1[4];
        #pragma unroll
        for (int q = 0; q < 4; ++q) {
            x0[q] = *(const float4*)(a0 + q * 4);
            x1[q] = *(const float4*)(a1 + q * 4);
        }
        short8 h8[2], l8[2];
        #pragma unroll
        for (int q = 0; q < 4; ++q) {
            const float m[4] = {0.5f * (x0[q].x + x1[q].x), 0.5f * (x0[q].y + x1[q].y),
                                0.5f * (x0[q].z + x1[q].z), 0.5f * (x0[q].w + x1[q].w)};
            #pragma unroll
            for (int e = 0; e < 4; ++e) {
                unsigned short hh, ll;
                split_bf16(m[e], hh, ll);
                h8[q >> 1][(q & 1) * 4 + e] = (short)hh;
                l8[q >> 1][(q & 1) * 4 + e] = (short)ll;
            }
        }
        const size_t hb = ((size_t)(mb * 32 + ach) * 128 + r) * 32 + k0;
        const size_t lb = ((size_t)(mb * 32 + 16 + ach) * 128 + r) * 32 + k0;
        *(short8*)(Ap + hb)     = h8[0];
        *(short8*)(Ap + hb + 8) = h8[1];
        *(short8*)(Ap + lb)     = l8[0];
        *(short8*)(Ap + lb + 8) = l8[1];
    }
}

// ---------------------------------------------------------------------------
// Kernel 2: pack B' images [colb 16][bch 32][row 128][k 32] + cb_sq; block 0
// zeros Sk / counter / loss. 64 blocks x 256 thr, 32 codes per block.
// ---------------------------------------------------------------------------
__global__ __launch_bounds__(256, 1)
void cra_pack_b(const float* __restrict__ cb,
                unsigned short* __restrict__ Bp,
                float* __restrict__ cb_sq,
                float* __restrict__ Sk,
                int* __restrict__ counter,
                float* __restrict__ loss_out)
{
    __shared__ float cbs[32 * D_DIM];    // 64 KB
    const int tid = threadIdx.x;
    const int c0  = blockIdx.x * 32;

    if (blockIdx.x == 0) {
        #pragma unroll
        for (int j = 0; j < 8; ++j) Sk[tid + j * 256] = 0.0f;
        if (tid == 0) { counter[0] = 0; loss_out[0] = 0.0f; }
    }

    {   // stage 32 codebook rows, coalesced float4
        const float4* src = (const float4*)(cb + (size_t)c0 * D_DIM);
        float4* dst = (float4*)cbs;
        #pragma unroll
        for (int k = 0; k < 16; ++k) dst[tid + k * 256] = src[tid + k * 256];
    }
    __syncthreads();

    if (tid < 32) {
        const float* r = cbs + tid * D_DIM;
        float s = 0.f;
        for (int d = 0; d < D_DIM; ++d) s = fmaf(r[d], r[d], s);
        cb_sq[c0 + tid] = s;
    }

    // pack: thread owns local row (tid>>3), elems dspan..dspan+63
    const int row  = tid >> 3;
    const int k    = c0 + row;
    const int colb = k >> 7;             // 0..15
    const int pr   = k & 127;
    const int dspan = (tid & 7) * 64;
    #pragma unroll
    for (int g = 0; g < 8; ++g) {
        const int d   = dspan + g * 8;
        const int bch = d >> 5;
        const int k0  = d & 31;
        short8 h8, l8;
        #pragma unroll
        for (int e = 0; e < 8; ++e) {
            unsigned short hh, ll;
            split_bf16(cbs[row * D_DIM + d + e], hh, ll);
            h8[e] = (short)hh; l8[e] = (short)ll;
        }
        *(short8*)(Bp + ((size_t)(colb * 32 + bch) * 128 + pr) * 32 + k0)      = h8;
        *(short8*)(Bp + ((size_t)(colb * 32 + 16 + bch) * 128 + pr) * 32 + k0) = l8;
    }
}

// ---------------------------------------------------------------------------
// Kernel 3: Sk[k] = ||cb[k]@W^T + pb - cb[k]||^2, atomically accumulated
// (Sk zeroed by pack_b). 256 blocks = 64 code-blocks x 4 e-blocks.
// ---------------------------------------------------------------------------
__global__ __launch_bounds__(256, 1)
void cra_proj(const float* __restrict__ cb,
              const float* __restrict__ W,
              const float* __restrict__ pb,
              float* __restrict__ Sk)
{
    __shared__ float cbs[32 * D_DIM];    // 64 KB
    __shared__ float red[4 * 32];
    const int tid = threadIdx.x;
    const int cblock = blockIdx.x >> 2;
    const int eb     = blockIdx.x & 3;
    const int c0 = cblock * 32;

    {
        const float4* src = (const float4*)(cb + (size_t)c0 * D_DIM);
        float4* dst = (float4*)cbs;
        #pragma unroll
        for (int k = 0; k < 16; ++k) dst[tid + k * 256] = src[tid + k * 256];
    }
    __syncthreads();

    const int e  = eb * 128 + (tid >> 1);
    const int dh = (tid & 1) * 256;
    float acc[32];
    #pragma unroll
    for (int c = 0; c < 32; ++c) acc[c] = 0.f;
    const float4* wrow = (const float4*)(W + (size_t)e * D_DIM + dh);
    for (int dq = 0; dq < 64; ++dq) {
        const float4 wv = wrow[dq];
        #pragma unroll
        for (int c = 0; c < 32; ++c) {
            const float4 cv = *(const float4*)&cbs[c * D_DIM + dh + dq * 4];
            acc[c] += cv.x * wv.x + cv.y * wv.y + cv.z * wv.z + cv.w * wv.w;
        }
    }
    const float bias = pb[e];
    const int w = tid >> 6;
    #pragma unroll
    for (int c = 0; c < 32; ++c) {
        const float full = acc[c] + __shfl_xor(acc[c], 1);
        const float diff = full + bias - cbs[c * D_DIM + e];
        float v = (tid & 1) ? 0.f : diff * diff;
        #pragma unroll
        for (int off = 32; off > 0; off >>= 1) v += __shfl_down(v, off, 64);
        if ((tid & 63) == 0) red[w * 32 + c] = v;
    }
    __syncthreads();
    if (tid < 32)
        atomicAdd(&Sk[c0 + tid],
                  red[tid] + red[32 + tid] + red[64 + tid] + red[96 + tid]);
}

// ---------------------------------------------------------------------------
// Kernel 4: zero-LDS register GEMM. 4096 blocks (256 mb x 16 colb, XCD
// swizzle as r5), 256 thr / 4 waves, tile 128x128, wave 64x64 = 4x4 of
// 16x16x32, K'=1536 (48 chunks). Frags loaded straight from the packed
// images: per (mi) sub-tile a wave's 64 lanes cover rows [base,base+16) x
// 64 B = one contiguous 1KB block (perfect coalescing). No main-loop LDS.
// ---------------------------------------------------------------------------
__global__ __launch_bounds__(256, 3)
void cra_gemm(const unsigned short* __restrict__ Ap,
              const unsigned short* __restrict__ Bp,
              const float* __restrict__ cb_sq,
              float4* __restrict__ wsRed)           // [32768][16] {v1,i1,v2,i2}
{
    __shared__ float4 sRed[128 * 8];     // 16 KB epilogue scratch only

    const int tid  = threadIdx.x;
    const int bid  = blockIdx.x;
    const int xcd  = bid & 7;
    const int slot = bid >> 3;           // 0..511
    const int mb   = xcd * 32 + (slot >> 4);
    const int colb = slot & 15;
    const int rowBase = mb * 128;
    const int colBase = colb * 128;

    const int lane = tid & 63;
    const int w    = tid >> 6;           // 0..3
    const int wr   = (w & 1) * 64;
    const int wcH  = w >> 1;             // 0..1
    const int wc   = wcH * 64;
    const int cid  = lane & 15;
    const int quad = lane >> 4;

    f32x4 acc[4][4];
    #pragma unroll
    for (int i = 0; i < 4; ++i)
        #pragma unroll
        for (int j = 0; j < 4; ++j) acc[i][j] = (f32x4)(0.f);

    // per-lane frag base pointers (shorts). Chunk image = 4096 shorts;
    // mi/ni stride = 16 rows * 32 = 512 shorts.
    const unsigned short* Abase = Ap + ((size_t)mb   * 32) * 4096 + (wr + cid) * 32 + quad * 8;
    const unsigned short* Bbase = Bp + ((size_t)colb * 32) * 4096 + (wc + cid) * 32 + quad * 8;

#define LOADF(af, bf, g) do {                                                  \
        const int ach_ = (g) & 31;                                             \
        const int bch_ = ((g) & 15) | (((g) & 32) >> 1);                       \
        const unsigned short* pa_ = Abase + ach_ * 4096;                       \
        const unsigned short* pb_ = Bbase + bch_ * 4096;                       \
        af[0] = *(const short8*)(pa_);        af[1] = *(const short8*)(pa_ + 512);  \
        af[2] = *(const short8*)(pa_ + 1024); af[3] = *(const short8*)(pa_ + 1536); \
        bf[0] = *(const short8*)(pb_);        bf[1] = *(const short8*)(pb_ + 512);  \
        bf[2] = *(const short8*)(pb_ + 1024); bf[3] = *(const short8*)(pb_ + 1536); \
    } while (0)

#define DOMFMA(af, bf) do {                                                    \
        __builtin_amdgcn_s_setprio(1);                                         \
        _Pragma("unroll")                                                      \
        for (int mi = 0; mi < 4; ++mi)                                         \
            _Pragma("unroll")                                                  \
            for (int ni = 0; ni < 4; ++ni)                                     \
                acc[mi][ni] = __builtin_amdgcn_mfma_f32_16x16x32_bf16(         \
                    af[mi], bf[ni], acc[mi][ni], 0, 0, 0);                     \
        __builtin_amdgcn_s_setprio(0);                                         \
    } while (0)

    // manual 2-deep pipeline, fully static indexing (two named frag sets)
    short8 afA[4], bfA[4], afB[4], bfB[4];
    LOADF(afA, bfA, 0);
    #pragma unroll 1
    for (int g = 0; g < 48; g += 2) {
        LOADF(afB, bfB, g + 1);          // prefetch odd chunk
        DOMFMA(afA, bfA);                // compute even chunk (order = r5)
        if (g + 2 < 48) LOADF(afA, bfA, g + 2);
        DOMFMA(afB, bfB);                // compute odd chunk
    }
#undef LOADF
#undef DOMFMA

    // ---- epilogue: score + top-2; C/D layout col=lane&15, row=quad*4+reg
    float cq[4];
    #pragma unroll
    for (int ni = 0; ni < 4; ++ni) cq[ni] = cb_sq[colBase + wc + ni * 16 + cid];

    #pragma unroll
    for (int mi = 0; mi < 4; ++mi) {
        #pragma unroll
        for (int reg = 0; reg < 4; ++reg) {
            float v1 = 3.4e38f, v2 = 3.4e38f;
            int   i1 = 0x7FFFFFFF, i2 = 0x7FFFFFFF;
            #pragma unroll
            for (int ni = 0; ni < 4; ++ni) {
                const float s = fmaf(-2.0f, acc[mi][ni][reg], cq[ni]);
                merge_cand(s, colBase + wc + ni * 16 + cid, v1, i1, v2, i2);
            }
            #pragma unroll
            for (int d = 1; d <= 2; d <<= 1) {
                float ov1 = __shfl_xor(v1, d); int oi1 = __shfl_xor(i1, d);
                float ov2 = __shfl_xor(v2, d); int oi2 = __shfl_xor(i2, d);
                merge_cand(ov1, oi1, v1, i1, v2, i2);
                merge_cand(ov2, oi2, v1, i1, v2, i2);
            }
            if ((cid & 3) == 0) {
                const int row = wr + mi * 16 + quad * 4 + reg;
                sRed[(row * 2 + wcH) * 4 + (cid >> 2)] =
                    make_float4(v1, __int_as_float(i1), v2, __int_as_float(i2));
            }
        }
    }
    __syncthreads();
    if (tid < 128) {
        float v1 = 3.4e38f, v2 = 3.4e38f;
        int   i1 = 0x7FFFFFFF, i2 = 0x7FFFFFFF;
        #pragma unroll
        for (int e = 0; e < 8; ++e) {
            const float4 t = sRed[tid * 8 + e];
            merge_cand(t.x, __float_as_int(t.y), v1, i1, v2, i2);
            merge_cand(t.z, __float_as_int(t.w), v1, i1, v2, i2);
        }
        wsRed[(size_t)(rowBase + tid) * 16 + colb] =
            make_float4(v1, __int_as_float(i1), v2, __int_as_float(i2));
    }
}

// ---------------------------------------------------------------------------
// Kernel 5: merge 16 colblock results per row; write idx, flag ties, loss.
// ---------------------------------------------------------------------------
__global__ __launch_bounds__(256, 1)
void cra_merge(const float4* __restrict__ wsRed,
               const float* __restrict__ Sk,
               float* __restrict__ out_idx,
               float* __restrict__ out_loss,
               int* __restrict__ counter,
               int* __restrict__ flagRow,
               int2* __restrict__ flagI)
{
    __shared__ float sl[256];
    const int tid = threadIdx.x;
    const int r = blockIdx.x * 256 + tid;
    float v1 = 3.4e38f, v2 = 3.4e38f;
    int   i1 = 0x7FFFFFFF, i2 = 0x7FFFFFFF;
    #pragma unroll 4
    for (int cbk = 0; cbk < 16; ++cbk) {
        const float4 t = wsRed[(size_t)r * 16 + cbk];
        merge_cand(t.x, __float_as_int(t.y), v1, i1, v2, i2);
        merge_cand(t.z, __float_as_int(t.w), v1, i1, v2, i2);
    }
    out_idx[r] = (float)i1;
    if (v2 - v1 < EPS_GAP) {
        const int slot = atomicAdd(counter, 1);
        flagRow[slot] = r;
        flagI[slot] = make_int2(i1, i2);
    }
    sl[tid] = Sk[i1];
    __syncthreads();
    for (int s = 128; s > 0; s >>= 1) { if (tid < s) sl[tid] += sl[tid + s]; __syncthreads(); }
    if (tid == 0) atomicAdd(out_loss, sl[0] * LOSS_SCALE);
}

// ---------------------------------------------------------------------------
// Kernel 6: gather embeddings (overwrites the A' image region).
// ---------------------------------------------------------------------------
__global__ __launch_bounds__(256, 1)
void cra_gather(const float* __restrict__ out_idx,
                const float4* __restrict__ cb4,
                float4* __restrict__ out4)
{
    __shared__ int sidx[128];
    const int tid = threadIdx.x;
    const int rb = blockIdx.x * 128;
    if (tid < 128) sidx[tid] = (int)out_idx[rb + tid];
    __syncthreads();
    for (int j = tid; j < 128 * 128; j += 256) {
        const int row = j >> 7, q = j & 127;
        out4[(size_t)(rb + row) * 128 + q] = cb4[(size_t)sidx[row] * 128 + q];
    }
}

// ---------------------------------------------------------------------------
// Kernel 7: exact-f32 recheck of flagged rows' top-2 candidates.
// ---------------------------------------------------------------------------
__global__ __launch_bounds__(256, 1)
void cra_recheck(const float* __restrict__ ce,
                 const float* __restrict__ cb,
                 const float* __restrict__ cb_sq,
                 const float* __restrict__ Sk,
                 const int* __restrict__ counter,
                 const int* __restrict__ flagRow,
                 const int2* __restrict__ flagI,
                 float* __restrict__ out_idx,
                 float4* __restrict__ out4,
                 float* __restrict__ out_loss,
                 const float4* __restrict__ cb4)
{
    __shared__ float rp[8];
    __shared__ int swin;
    const int tid = threadIdx.x;
    const int n = counter[0];
    for (int f = blockIdx.x; f < n; f += 64) {
        const int row = flagRow[f];
        const int2 ii = flagI[f];
        const int d0 = tid * 2;
        const float2 x0 = *(const float2*)(ce + (size_t)(2 * row) * D_DIM + d0);
        const float2 x1 = *(const float2*)(ce + (size_t)(2 * row) * D_DIM + D_DIM + d0);
        const float m0 = 0.5f * (x0.x + x1.x), m1 = 0.5f * (x0.y + x1.y);
        const float* c1 = cb + (size_t)ii.x * D_DIM + d0;
        const float* c2 = cb + (size_t)ii.y * D_DIM + d0;
        float p1 = fmaf(m0, c1[0], m1 * c1[1]);
        float p2 = fmaf(m0, c2[0], m1 * c2[1]);
        #pragma unroll
        for (int off = 32; off > 0; off >>= 1) {
            p1 += __shfl_down(p1, off, 64);
            p2 += __shfl_down(p2, off, 64);
        }
        if ((tid & 63) == 0) { rp[(tid >> 6) * 2] = p1; rp[(tid >> 6) * 2 + 1] = p2; }
        __syncthreads();
        if (tid == 0) {
            const float dot1 = rp[0] + rp[2] + rp[4] + rp[6];
            const float dot2 = rp[1] + rp[3] + rp[5] + rp[7];
            const float s1 = cb_sq[ii.x] - 2.f * dot1;
            const float s2 = cb_sq[ii.y] - 2.f * dot2;
            const int win = (s2 < s1 || (s2 == s1 && ii.y < ii.x)) ? ii.y : ii.x;
            swin = win;
            if (win != ii.x) {
                out_idx[row] = (float)win;
                atomicAdd(out_loss, (Sk[win] - Sk[ii.x]) * LOSS_SCALE);
            }
        }
        __syncthreads();
        if (swin != ii.x) {
            for (int q = tid; q < 128; q += 256)
                out4[(size_t)row * 128 + q] = cb4[(size_t)swin * 128 + q];
        }
        __syncthreads();
    }
}

// ---------------------------------------------------------------------------
extern "C" void kernel_launch(void* const* d_in, const int* in_sizes, int n_in,
                              void* d_out, int out_size, void* d_ws, size_t ws_size,
                              hipStream_t stream)
{
    // inputs: 0 char_tokens (unused), 1 char_embeddings, 2 word_codebook,
    //         3 proj_w, 4 proj_b
    const float* ce = (const float*)d_in[1];
    const float* cb = (const float*)d_in[2];
    const float* W  = (const float*)d_in[3];
    const float* pb = (const float*)d_in[4];

    char* ws = (char*)d_ws;                                  // ~13 MB used
    unsigned short* Bp = (unsigned short*)ws;                // 4 MB B' images
    float4* wsRed  = (float4*)(ws + 4194304);                // 8 MB top-2 scratch
    float* cb_sq   = (float*)(ws + 12582912);
    float* Sk      = (float*)(ws + 12582912 + 8192);
    int*   flagRow = (int*)(ws + 12582912 + 16384);
    int2*  flagI   = (int2*)(ws + 12582912 + 16384 + 131072);
    int*   counter = (int*)(ws + 12582912 + 16384 + 131072 + 262144);

    float* out_idx  = (float*)d_out;
    float* out_emb  = out_idx + N_ROWS;
    float* out_loss = out_emb + (size_t)N_ROWS * D_DIM;
    // A' images (64 MiB) live in the emb output region until gather overwrites.
    unsigned short* Ap = (unsigned short*)out_emb;

    cra_pack_a<<<256, 256, 0, stream>>>(ce, Ap);
    cra_pack_b<<<64, 256, 0, stream>>>(cb, Bp, cb_sq, Sk, counter, out_loss);
    cra_proj<<<256, 256, 0, stream>>>(cb, W, pb, Sk);
    cra_gemm<<<4096, 256, 0, stream>>>(Ap, Bp, cb_sq, wsRed);
    cra_merge<<<128, 256, 0, stream>>>(wsRed, Sk, out_idx, out_loss, counter, flagRow, flagI);
    cra_gather<<<256, 256, 0, stream>>>(out_idx, (const float4*)cb, (float4*)out_emb);
    cra_recheck<<<64, 256, 0, stream>>>(ce, cb, cb_sq, Sk, counter, flagRow, flagI,
                                        out_idx, (float4*)out_emb, out_loss, (const float4*)cb);
}

// Round 5
// 872.672 us; speedup vs baseline: 1.2115x; 1.2115x over previous
//
#include <hip/hip_runtime.h>

// SimpleCRA round 10: byte-cut 128x256-tile GEMM, 8-wave blocks, 2 blocks/CU.
// Model from r5-r9: time = VMEM-bytes-per-CU / ~9-13 B/cy, rate needs >=2-3
// independent issue groups per CU (r8's single 16-wave lockstep got 3.8 B/cy).
// This round: tile 128x256 => staged bytes 3.2GB -> 2.36GB (-26%) while
// keeping 2 blocks/CU (8 waves x <=128 regs):
//   - 2048 blocks (256 mb x 8 cb, bijective XCD swizzle), 512 thr / 8 waves
//   - wave tile 64x64 (2M x 4N wave grid), acc 64 f32 -> ~120 regs
//   - LDS 72KB = 3 buffers x (A 8K + B 16K); 2 blocks/CU (144KB)
//   - counted vmcnt(3), stage(g+2) issued EARLY (top of iter, freed buffer)
// Chunk order g=0..47 (ah*bh, al*bh, ah*bl) and frag slicing identical to
// r5 => bitwise-identical scores; EPS/tie-recheck path untouched.
// pack_a/pack_b/proj/gather/recheck = r5 verbatim; merge = 8-wide (wsRed[.][8]).

#define D_DIM    512
#define K_CODES  2048
#define N_ROWS   32768
#define EPS_GAP  1e-5f
#define LOSS_SCALE (1.0f / 16777216.0f)   // 1/(N_ROWS*D_DIM)

typedef __attribute__((ext_vector_type(8))) short short8;   // 8 bf16 (4 VGPR)
typedef __attribute__((ext_vector_type(4))) float f32x4;    // MFMA C/D

__device__ __forceinline__ void split_bf16(float f, unsigned short& h, unsigned short& l) {
    unsigned u = __float_as_uint(f);
    h = (unsigned short)(u >> 16);                       // truncation split
    float hr = __uint_as_float(u & 0xFFFF0000u);
    l = (unsigned short)(__float_as_uint(f - hr) >> 16);
}

// async global->LDS DMA, 16 B/lane; lds ptr wave-uniform, HW adds lane*16.
__device__ __forceinline__ void dma16(const void* g, void* l) {
    __builtin_amdgcn_global_load_lds(
        (const __attribute__((address_space(1))) unsigned int*)g,
        (__attribute__((address_space(3))) unsigned int*)l, 16, 0, 0);
}

// insert candidate into sorted-2 list ordered by (val, idx) — total order,
// merge-order independent; matches numpy first-occurrence argmin.
__device__ __forceinline__ void merge_cand(float s, int idx, float& v1, int& i1, float& v2, int& i2) {
    if (s < v1 || (s == v1 && idx < i1)) { v2 = v1; i2 = i1; v1 = s; i1 = idx; }
    else if (s < v2 || (s == v2 && idx < i2)) { v2 = s; i2 = idx; }
}

// ---------------------------------------------------------------------------
// Kernel 1: pack A' images. Block = one mb (128 mean-rows); layout
// [mb 256][ach 32][row 128][k 32] shorts, ach 0-15 = Ah, 16-31 = Al.
// ---------------------------------------------------------------------------
__global__ __launch_bounds__(256, 1)
void cra_pack_a(const float* __restrict__ ce,
                unsigned short* __restrict__ Ap)
{
    const int tid = threadIdx.x;
    const int mb  = blockIdx.x;
    const int rq  = tid >> 5;            // row slice 0..7
    const int dq  = tid & 31;            // 16-float span index
    const int dbase = dq * 16;
    const int ach = dq >> 1;             // 0..15
    const int k0  = (dq & 1) * 16;

    #pragma unroll 2
    for (int p = 0; p < 16; ++p) {
        const int r  = p * 8 + rq;       // 0..127
        const int gr = mb * 128 + r;
        const float* a0 = ce + (size_t)(2 * gr) * D_DIM + dbase;
        const float* a1 = a0 + D_DIM;
        float4 x0[4], x1[4];
        #pragma unroll
        for (int q = 0; q < 4; ++q) {
            x0[q] = *(const float4*)(a0 + q * 4);
            x1[q] = *(const float4*)(a1 + q * 4);
        }
        short8 h8[2], l8[2];
        #pragma unroll
        for (int q = 0; q < 4; ++q) {
            const float m[4] = {0.5f * (x0[q].x + x1[q].x), 0.5f * (x0[q].y + x1[q].y),
                                0.5f * (x0[q].z + x1[q].z), 0.5f * (x0[q].w + x1[q].w)};
            #pragma unroll
            for (int e = 0; e < 4; ++e) {
                unsigned short hh, ll;
                split_bf16(m[e], hh, ll);
                h8[q >> 1][(q & 1) * 4 + e] = (short)hh;
                l8[q >> 1][(q & 1) * 4 + e] = (short)ll;
            }
        }
        const size_t hb = ((size_t)(mb * 32 + ach) * 128 + r) * 32 + k0;
        const size_t lb = ((size_t)(mb * 32 + 16 + ach) * 128 + r) * 32 + k0;
        *(short8*)(Ap + hb)     = h8[0];
        *(short8*)(Ap + hb + 8) = h8[1];
        *(short8*)(Ap + lb)     = l8[0];
        *(short8*)(Ap + lb + 8) = l8[1];
    }
}

// ---------------------------------------------------------------------------
// Kernel 2: pack B' images [colb 16][bch 32][row 128][k 32] + cb_sq; block 0
// zeros Sk / counter / loss. 64 blocks x 256 thr, 32 codes per block.
// ---------------------------------------------------------------------------
__global__ __launch_bounds__(256, 1)
void cra_pack_b(const float* __restrict__ cb,
                unsigned short* __restrict__ Bp,
                float* __restrict__ cb_sq,
                float* __restrict__ Sk,
                int* __restrict__ counter,
                float* __restrict__ loss_out)
{
    __shared__ float cbs[32 * D_DIM];    // 64 KB
    const int tid = threadIdx.x;
    const int c0  = blockIdx.x * 32;

    if (blockIdx.x == 0) {
        #pragma unroll
        for (int j = 0; j < 8; ++j) Sk[tid + j * 256] = 0.0f;
        if (tid == 0) { counter[0] = 0; loss_out[0] = 0.0f; }
    }

    {   // stage 32 codebook rows, coalesced float4
        const float4* src = (const float4*)(cb + (size_t)c0 * D_DIM);
        float4* dst = (float4*)cbs;
        #pragma unroll
        for (int k = 0; k < 16; ++k) dst[tid + k * 256] = src[tid + k * 256];
    }
    __syncthreads();

    if (tid < 32) {
        const float* r = cbs + tid * D_DIM;
        float s = 0.f;
        for (int d = 0; d < D_DIM; ++d) s = fmaf(r[d], r[d], s);
        cb_sq[c0 + tid] = s;
    }

    // pack: thread owns local row (tid>>3), elems dspan..dspan+63
    const int row  = tid >> 3;
    const int k    = c0 + row;
    const int colb = k >> 7;             // 0..15
    const int pr   = k & 127;
    const int dspan = (tid & 7) * 64;
    #pragma unroll
    for (int g = 0; g < 8; ++g) {
        const int d   = dspan + g * 8;
        const int bch = d >> 5;
        const int k0  = d & 31;
        short8 h8, l8;
        #pragma unroll
        for (int e = 0; e < 8; ++e) {
            unsigned short hh, ll;
            split_bf16(cbs[row * D_DIM + d + e], hh, ll);
            h8[e] = (short)hh; l8[e] = (short)ll;
        }
        *(short8*)(Bp + ((size_t)(colb * 32 + bch) * 128 + pr) * 32 + k0)      = h8;
        *(short8*)(Bp + ((size_t)(colb * 32 + 16 + bch) * 128 + pr) * 32 + k0) = l8;
    }
}

// ---------------------------------------------------------------------------
// Kernel 3: Sk[k] = ||cb[k]@W^T + pb - cb[k]||^2, atomically accumulated
// (Sk zeroed by pack_b). 256 blocks = 64 code-blocks x 4 e-blocks.
// ---------------------------------------------------------------------------
__global__ __launch_bounds__(256, 1)
void cra_proj(const float* __restrict__ cb,
              const float* __restrict__ W,
              const float* __restrict__ pb,
              float* __restrict__ Sk)
{
    __shared__ float cbs[32 * D_DIM];    // 64 KB
    __shared__ float red[4 * 32];
    const int tid = threadIdx.x;
    const int cblock = blockIdx.x >> 2;
    const int eb     = blockIdx.x & 3;
    const int c0 = cblock * 32;

    {
        const float4* src = (const float4*)(cb + (size_t)c0 * D_DIM);
        float4* dst = (float4*)cbs;
        #pragma unroll
        for (int k = 0; k < 16; ++k) dst[tid + k * 256] = src[tid + k * 256];
    }
    __syncthreads();

    const int e  = eb * 128 + (tid >> 1);
    const int dh = (tid & 1) * 256;
    float acc[32];
    #pragma unroll
    for (int c = 0; c < 32; ++c) acc[c] = 0.f;
    const float4* wrow = (const float4*)(W + (size_t)e * D_DIM + dh);
    for (int dq = 0; dq < 64; ++dq) {
        const float4 wv = wrow[dq];
        #pragma unroll
        for (int c = 0; c < 32; ++c) {
            const float4 cv = *(const float4*)&cbs[c * D_DIM + dh + dq * 4];
            acc[c] += cv.x * wv.x + cv.y * wv.y + cv.z * wv.z + cv.w * wv.w;
        }
    }
    const float bias = pb[e];
    const int w = tid >> 6;
    #pragma unroll
    for (int c = 0; c < 32; ++c) {
        const float full = acc[c] + __shfl_xor(acc[c], 1);
        const float diff = full + bias - cbs[c * D_DIM + e];
        float v = (tid & 1) ? 0.f : diff * diff;
        #pragma unroll
        for (int off = 32; off > 0; off >>= 1) v += __shfl_down(v, off, 64);
        if ((tid & 63) == 0) red[w * 32 + c] = v;
    }
    __syncthreads();
    if (tid < 32)
        atomicAdd(&Sk[c0 + tid],
                  red[tid] + red[32 + tid] + red[64 + tid] + red[96 + tid]);
}

// ---------------------------------------------------------------------------
// Kernel 4: 128x256-tile GEMM, 8 waves (2M x 4N), 3-buffer counted vmcnt.
// 2048 blocks (256 mb x 8 cb, bijective XCD swizzle), 512 thr.
// Per chunk: stage A 8KB (r5 A-image) + B 16KB (two adjacent B-images
// 2cb, 2cb+1) = 24 x 1KB segs; wave w stages segs {3w..3w+2}.
// ---------------------------------------------------------------------------
__global__ __launch_bounds__(512, 4)
void cra_gemm(const unsigned short* __restrict__ Ap,
              const unsigned short* __restrict__ Bp,
              const float* __restrict__ cb_sq,
              float4* __restrict__ wsRed)           // [32768][8] {v1,i1,v2,i2}
{
    __shared__ __align__(16) char sMem[3 * 24576];  // 72 KB: 3 x (A 8K + B 16K)

    const int tid  = threadIdx.x;
    const int bid  = blockIdx.x;
    const int wgid = (bid & 7) * 256 + (bid >> 3);  // bijective, nwg=2048
    const int mb   = wgid >> 3;          // 0..255 (128-row tile)
    const int cb   = wgid & 7;           // 0..7   (256-col tile)
    const int rowBase = mb * 128;
    const int colBase = cb * 256;

    const int lane = tid & 63;
    const int w    = tid >> 6;           // 0..7
    const int wm   = w >> 2;             // 0..1 (row half)
    const int wn   = w & 3;              // 0..3 (col quarter)
    const int cid  = lane & 15;
    const int quad = lane >> 4;

    f32x4 acc[4][4];
    #pragma unroll
    for (int i = 0; i < 4; ++i)
        #pragma unroll
        for (int j = 0; j < 4; ++j) acc[i][j] = (f32x4)(0.f);

    // stage sources (lane*16 folded in; dst is wave-uniform, HW adds lane*16)
    const char* ApC  = (const char*)Ap + ((size_t)mb * 32) * 8192 + lane * 16;
    const char* BpC0 = (const char*)Bp + ((size_t)(2 * cb)     * 32) * 8192 + lane * 16;
    const char* BpC1 = (const char*)Bp + ((size_t)(2 * cb + 1) * 32) * 8192 + lane * 16;
    const int s0 = 3 * w;                // this wave's first seg (0..21)

    auto stage = [&](int g, int p) {
        const int ach = g & 31;
        const int bch = (g & 15) | ((g & 32) >> 1);
        char* dstBase = (char*)sMem + p * 24576;
        #pragma unroll
        for (int j = 0; j < 3; ++j) {
            const int s = s0 + j;        // wave-uniform
            const char* src;
            if (s < 8)       src = ApC  + ach * 8192 + s * 1024;
            else if (s < 16) src = BpC0 + bch * 8192 + (s - 8) * 1024;
            else             src = BpC1 + bch * 8192 + (s - 16) * 1024;
            dma16(src, dstBase + s * 1024);
        }
    };

    // prologue: chunks 0,1 in flight (6 loads/wave outstanding)
    stage(0, 0);
    stage(1, 1);

    #pragma unroll 1
    for (int g = 0; g < 48; ++g) {
        const int p = g % 3;
        // FIFO vmcnt: all but the newest 3 (chunk g+1) drained => chunk g
        // landed. Barrier aligns all waves => buffer complete block-wide.
        if (g < 47) asm volatile("s_waitcnt vmcnt(3)\n\ts_barrier" ::: "memory");
        else        asm volatile("s_waitcnt vmcnt(0)\n\ts_barrier" ::: "memory");

        // issue-early: buffer (g+2)%3 == (g-1)%3 was fully read in iter g-1
        // (fenced by its lgkmcnt(0)+barrier) -> stage now, overlap with MFMA.
        if (g + 2 < 48) stage(g + 2, (g + 2) % 3);

        const short* sA = (const short*)(sMem + p * 24576);
        const short* sB = (const short*)(sMem + p * 24576 + 8192 + (wn >> 1) * 8192);

        short8 aF[4], bF[4];
        #pragma unroll
        for (int mi = 0; mi < 4; ++mi)
            aF[mi] = *(const short8*)&sA[(wm * 64 + mi * 16 + cid) * 32 + quad * 8];
        #pragma unroll
        for (int ni = 0; ni < 4; ++ni)
            bF[ni] = *(const short8*)&sB[((wn & 1) * 64 + ni * 16 + cid) * 32 + quad * 8];
        __builtin_amdgcn_s_setprio(1);
        #pragma unroll
        for (int mi = 0; mi < 4; ++mi)
            #pragma unroll
            for (int ni = 0; ni < 4; ++ni)
                acc[mi][ni] = __builtin_amdgcn_mfma_f32_16x16x32_bf16(aF[mi], bF[ni], acc[mi][ni], 0, 0, 0);
        __builtin_amdgcn_s_setprio(0);

        // this wave's LDS reads retired; after barrier, buf p is reusable.
        asm volatile("s_waitcnt lgkmcnt(0)\n\ts_barrier" ::: "memory");
    }

    // ---- epilogue: score + top-2; C/D layout col=cid, row=quad*4+reg
    float cq[4];
    #pragma unroll
    for (int ni = 0; ni < 4; ++ni) cq[ni] = cb_sq[colBase + wn * 64 + ni * 16 + cid];

    __syncthreads();                     // reuse sMem as reduction scratch
    float4* sRed = (float4*)sMem;        // [row 128][wn 4][slot 4] = 32 KB
    #pragma unroll
    for (int mi = 0; mi < 4; ++mi) {
        #pragma unroll
        for (int reg = 0; reg < 4; ++reg) {
            float v1 = 3.4e38f, v2 = 3.4e38f;
            int   i1 = 0x7FFFFFFF, i2 = 0x7FFFFFFF;
            #pragma unroll
            for (int ni = 0; ni < 4; ++ni) {
                const float s = fmaf(-2.0f, acc[mi][ni][reg], cq[ni]);
                merge_cand(s, colBase + wn * 64 + ni * 16 + cid, v1, i1, v2, i2);
            }
            #pragma unroll
            for (int d = 1; d <= 2; d <<= 1) {
                float ov1 = __shfl_xor(v1, d); int oi1 = __shfl_xor(i1, d);
                float ov2 = __shfl_xor(v2, d); int oi2 = __shfl_xor(i2, d);
                merge_cand(ov1, oi1, v1, i1, v2, i2);
                merge_cand(ov2, oi2, v1, i1, v2, i2);
            }
            if ((cid & 3) == 0) {
                const int row = wm * 64 + mi * 16 + quad * 4 + reg;   // 0..127
                sRed[(row * 4 + wn) * 4 + (cid >> 2)] =
                    make_float4(v1, __int_as_float(i1), v2, __int_as_float(i2));
            }
        }
    }
    __syncthreads();
    if (tid < 128) {
        float v1 = 3.4e38f, v2 = 3.4e38f;
        int   i1 = 0x7FFFFFFF, i2 = 0x7FFFFFFF;
        #pragma unroll
        for (int e = 0; e < 16; ++e) {
            const float4 t = sRed[tid * 16 + e];
            merge_cand(t.x, __float_as_int(t.y), v1, i1, v2, i2);
            merge_cand(t.z, __float_as_int(t.w), v1, i1, v2, i2);
        }
        wsRed[(size_t)(rowBase + tid) * 8 + cb] =
            make_float4(v1, __int_as_float(i1), v2, __int_as_float(i2));
    }
}

// ---------------------------------------------------------------------------
// Kernel 5: merge 8 colblock results per row; write idx, flag ties, loss.
// ---------------------------------------------------------------------------
__global__ __launch_bounds__(256, 1)
void cra_merge(const float4* __restrict__ wsRed,
               const float* __restrict__ Sk,
               float* __restrict__ out_idx,
               float* __restrict__ out_loss,
               int* __restrict__ counter,
               int* __restrict__ flagRow,
               int2* __restrict__ flagI)
{
    __shared__ float sl[256];
    const int tid = threadIdx.x;
    const int r = blockIdx.x * 256 + tid;
    float v1 = 3.4e38f, v2 = 3.4e38f;
    int   i1 = 0x7FFFFFFF, i2 = 0x7FFFFFFF;
    #pragma unroll 4
    for (int cbk = 0; cbk < 8; ++cbk) {
        const float4 t = wsRed[(size_t)r * 8 + cbk];
        merge_cand(t.x, __float_as_int(t.y), v1, i1, v2, i2);
        merge_cand(t.z, __float_as_int(t.w), v1, i1, v2, i2);
    }
    out_idx[r] = (float)i1;
    if (v2 - v1 < EPS_GAP) {
        const int slot = atomicAdd(counter, 1);
        flagRow[slot] = r;
        flagI[slot] = make_int2(i1, i2);
    }
    sl[tid] = Sk[i1];
    __syncthreads();
    for (int s = 128; s > 0; s >>= 1) { if (tid < s) sl[tid] += sl[tid + s]; __syncthreads(); }
    if (tid == 0) atomicAdd(out_loss, sl[0] * LOSS_SCALE);
}

// ---------------------------------------------------------------------------
// Kernel 6: gather embeddings (overwrites the A' image region).
// ---------------------------------------------------------------------------
__global__ __launch_bounds__(256, 1)
void cra_gather(const float* __restrict__ out_idx,
                const float4* __restrict__ cb4,
                float4* __restrict__ out4)
{
    __shared__ int sidx[128];
    const int tid = threadIdx.x;
    const int rb = blockIdx.x * 128;
    if (tid < 128) sidx[tid] = (int)out_idx[rb + tid];
    __syncthreads();
    for (int j = tid; j < 128 * 128; j += 256) {
        const int row = j >> 7, q = j & 127;
        out4[(size_t)(rb + row) * 128 + q] = cb4[(size_t)sidx[row] * 128 + q];
    }
}

// ---------------------------------------------------------------------------
// Kernel 7: exact-f32 recheck of flagged rows' top-2 candidates.
// ---------------------------------------------------------------------------
__global__ __launch_bounds__(256, 1)
void cra_recheck(const float* __restrict__ ce,
                 const float* __restrict__ cb,
                 const float* __restrict__ cb_sq,
                 const float* __restrict__ Sk,
                 const int* __restrict__ counter,
                 const int* __restrict__ flagRow,
                 const int2* __restrict__ flagI,
                 float* __restrict__ out_idx,
                 float4* __restrict__ out4,
                 float* __restrict__ out_loss,
                 const float4* __restrict__ cb4)
{
    __shared__ float rp[8];
    __shared__ int swin;
    const int tid = threadIdx.x;
    const int n = counter[0];
    for (int f = blockIdx.x; f < n; f += 64) {
        const int row = flagRow[f];
        const int2 ii = flagI[f];
        const int d0 = tid * 2;
        const float2 x0 = *(const float2*)(ce + (size_t)(2 * row) * D_DIM + d0);
        const float2 x1 = *(const float2*)(ce + (size_t)(2 * row) * D_DIM + D_DIM + d0);
        const float m0 = 0.5f * (x0.x + x1.x), m1 = 0.5f * (x0.y + x1.y);
        const float* c1 = cb + (size_t)ii.x * D_DIM + d0;
        const float* c2 = cb + (size_t)ii.y * D_DIM + d0;
        float p1 = fmaf(m0, c1[0], m1 * c1[1]);
        float p2 = fmaf(m0, c2[0], m1 * c2[1]);
        #pragma unroll
        for (int off = 32; off > 0; off >>= 1) {
            p1 += __shfl_down(p1, off, 64);
            p2 += __shfl_down(p2, off, 64);
        }
        if ((tid & 63) == 0) { rp[(tid >> 6) * 2] = p1; rp[(tid >> 6) * 2 + 1] = p2; }
        __syncthreads();
        if (tid == 0) {
            const float dot1 = rp[0] + rp[2] + rp[4] + rp[6];
            const float dot2 = rp[1] + rp[3] + rp[5] + rp[7];
            const float s1 = cb_sq[ii.x] - 2.f * dot1;
            const float s2 = cb_sq[ii.y] - 2.f * dot2;
            const int win = (s2 < s1 || (s2 == s1 && ii.y < ii.x)) ? ii.y : ii.x;
            swin = win;
            if (win != ii.x) {
                out_idx[row] = (float)win;
                atomicAdd(out_loss, (Sk[win] - Sk[ii.x]) * LOSS_SCALE);
            }
        }
        __syncthreads();
        if (swin != ii.x) {
            for (int q = tid; q < 128; q += 256)
                out4[(size_t)row * 128 + q] = cb4[(size_t)swin * 128 + q];
        }
        __syncthreads();
    }
}

// ---------------------------------------------------------------------------
extern "C" void kernel_launch(void* const* d_in, const int* in_sizes, int n_in,
                              void* d_out, int out_size, void* d_ws, size_t ws_size,
                              hipStream_t stream)
{
    // inputs: 0 char_tokens (unused), 1 char_embeddings, 2 word_codebook,
    //         3 proj_w, 4 proj_b
    const float* ce = (const float*)d_in[1];
    const float* cb = (const float*)d_in[2];
    const float* W  = (const float*)d_in[3];
    const float* pb = (const float*)d_in[4];

    char* ws = (char*)d_ws;                                  // ~13 MB used
    unsigned short* Bp = (unsigned short*)ws;                // 4 MB B' images
    float4* wsRed  = (float4*)(ws + 4194304);                // 4 MB top-2 scratch
    float* cb_sq   = (float*)(ws + 12582912);
    float* Sk      = (float*)(ws + 12582912 + 8192);
    int*   flagRow = (int*)(ws + 12582912 + 16384);
    int2*  flagI   = (int2*)(ws + 12582912 + 16384 + 131072);
    int*   counter = (int*)(ws + 12582912 + 16384 + 131072 + 262144);

    float* out_idx  = (float*)d_out;
    float* out_emb  = out_idx + N_ROWS;
    float* out_loss = out_emb + (size_t)N_ROWS * D_DIM;
    // A' images (64 MiB) live in the emb output region until gather overwrites.
    unsigned short* Ap = (unsigned short*)out_emb;

    cra_pack_a<<<256, 256, 0, stream>>>(ce, Ap);
    cra_pack_b<<<64, 256, 0, stream>>>(cb, Bp, cb_sq, Sk, counter, out_loss);
    cra_proj<<<256, 256, 0, stream>>>(cb, W, pb, Sk);
    cra_gemm<<<2048, 512, 0, stream>>>(Ap, Bp, cb_sq, wsRed);
    cra_merge<<<128, 256, 0, stream>>>(wsRed, Sk, out_idx, out_loss, counter, flagRow, flagI);
    cra_gather<<<256, 256, 0, stream>>>(out_idx, (const float4*)cb, (float4*)out_emb);
    cra_recheck<<<64, 256, 0, stream>>>(ce, cb, cb_sq, Sk, counter, flagRow, flagI,
                                        out_idx, (float4*)out_emb, out_loss, (const float4*)cb);
}